// Round 7
// baseline (405.451 us; speedup 1.0000x reference)
//
#include <hip/hip_runtime.h>

typedef __attribute__((ext_vector_type(8))) short s8v;
typedef __attribute__((ext_vector_type(4))) short s4v;
typedef __attribute__((ext_vector_type(4))) float f4v;
typedef __attribute__((ext_vector_type(4))) unsigned int u4v;

#define LOG2E 1.44269504088896340736f

__device__ __forceinline__ unsigned short f2bf(float f) {
    unsigned int x = __float_as_uint(f);
    return (unsigned short)((x + 0x7fffu + ((x >> 16) & 1u)) >> 16);
}
__device__ __forceinline__ s8v ld8(const unsigned short* p) {
    return *(const s8v*)p;
}

// async global->LDS, 16B per lane; LDS dest is wave-uniform base + lane*16
#define GLOAD_LDS(g, l) __builtin_amdgcn_global_load_lds(              \
    (const __attribute__((address_space(1))) void*)(const void*)(g),   \
    (__attribute__((address_space(3))) void*)(void*)(l), 16, 0, 0)

// ------- 4x W transpose + fp32->bf16 in one launch -------------------------
__global__ __launch_bounds__(256) void transpose_w4(
    const float* __restrict__ W0, const float* __restrict__ W1,
    const float* __restrict__ W2, const float* __restrict__ W3,
    unsigned short* __restrict__ T0, unsigned short* __restrict__ T1,
    unsigned short* __restrict__ T2, unsigned short* __restrict__ T3)
{
    __shared__ float tile[32][33];
    int z = blockIdx.z;
    const float* W = z == 0 ? W0 : z == 1 ? W1 : z == 2 ? W2 : W3;
    unsigned short* Wt = z == 0 ? T0 : z == 1 ? T1 : z == 2 ? T2 : T3;
    int tx = threadIdx.x, ty = threadIdx.y;
    int x = blockIdx.x * 32 + tx;
#pragma unroll
    for (int i = 0; i < 4; i++) {
        int y = blockIdx.y * 32 + ty + i * 8;
        tile[ty + i * 8][tx] = W[y * 1024 + x];
    }
    __syncthreads();
    int x2 = blockIdx.y * 32 + tx;
#pragma unroll
    for (int i = 0; i < 4; i++) {
        int y2 = blockIdx.x * 32 + ty + i * 8;
        Wt[y2 * 1024 + x2] = f2bf(tile[tx][ty + i * 8]);
    }
}

// ------- fused QKV GEMM, 256x256 tile (m248-class 2-phase) -----------------
// {q,k,v}[8192,1024]fp32 @ W^T + bias.  8 waves (2M x 4N), wave tile 128x64,
// BK=32, LDS 64 KB (A+B double-buffered).  A fp32 reg-staged + cvt_pk +
// XOR-swizzled ds_write (both-sides involution byte^((row&7)<<4)); B bf16
// via global_load_lds w16 (linear).  32 MFMA per K-step, 1 barrier/step.
// NOTE: no min-waves in launch_bounds — acc[8][4] alone is 128 VGPR, so a
// 2-blocks/CU bound (128-VGPR cap) would force ~100 regs of K-loop spill.
// Grid 384 = 8 xcd x 4 Mpanel x 12 Ncol; z = col-tile>>2 picks Q/K/V.
// z=0: qw [b,h,l,d] * sscale.  z=1: kw [b,h,l,d].  z=2: vtw [b,h,d,l'],
// l' = key-permuted low-6 bits (PV fragment layout).
__global__ __launch_bounds__(512) void qkv_gemm(
    const float* __restrict__ Aq, const float* __restrict__ Ak,
    const float* __restrict__ Avv,
    const unsigned short* __restrict__ BtQ, const unsigned short* __restrict__ BtK,
    const unsigned short* __restrict__ BtV,
    const float* __restrict__ bq, const float* __restrict__ bk,
    const float* __restrict__ bv,
    unsigned short* __restrict__ qo, unsigned short* __restrict__ ko,
    unsigned short* __restrict__ vo, float sscale)
{
    __shared__ __align__(16) unsigned short ldsA[2][256 * 32];
    __shared__ __align__(16) unsigned short ldsB[2][256 * 32];

    // bijective 384 = 8 xcd x 48: each XCD owns 4 M-panels x all 12 N-tiles
    int i = blockIdx.x;
    int c = i & 7, j = i >> 3;       // j 0..47
    int by = c * 4 + (j & 3);        // 0..31
    int bx = j >> 2;                 // 0..11

    int z = bx >> 2;                 // 0:Q 1:K 2:V
    const float* A = z == 0 ? Aq : z == 1 ? Ak : Avv;
    const unsigned short* Bt = z == 0 ? BtQ : z == 1 ? BtK : BtV;
    const float* bias = z == 0 ? bq : z == 1 ? bk : bv;
    unsigned short* out = z == 0 ? qo : z == 1 ? ko : vo;
    float oscale = z == 0 ? sscale : 1.0f;

    int m0 = by * 256;
    int n0 = (bx & 3) * 256;         // within the 1024-wide matrix

    int tid = threadIdx.x;
    int w = tid >> 6, lane = tid & 63;
    int quad = lane >> 4, l15 = lane & 15;
    int wr = w >> 2, wc = w & 3;     // 2 x 4 wave grid

    // A staging: thread -> (row = tid>>1, half = tid&1 of 32 floats)
    int arow = tid >> 1, ahalf = tid & 1;
    const float* ap = A + (size_t)(m0 + arow) * 1024 + ahalf * 16;
    int ab = arow * 64 + ahalf * 32;          // byte offset in A tile
    int aswz = (arow & 7) << 4;
    int awb0 = ab ^ aswz, awb1 = (ab + 16) ^ aswz;

    // B staging: chunks tid and tid+512; chunk -> row=chunk>>2, k=(chunk&3)*8
    const unsigned short* bp = Bt + (size_t)(n0 + (tid >> 2)) * 1024 + (tid & 3) * 8;

    f4v acc[8][4];
#pragma unroll
    for (int m = 0; m < 8; m++)
#pragma unroll
        for (int n = 0; n < 4; n++) { f4v zz = {0.f, 0.f, 0.f, 0.f}; acc[m][n] = zz; }

    auto stageB = [&](int buf, int k0) {
        GLOAD_LDS(bp + k0, &ldsB[buf][w * 512]);
        GLOAD_LDS(bp + k0 + (size_t)128 * 1024, &ldsB[buf][4096 + w * 512]);
    };
    auto cvtwrA = [&](int buf, f4v a0, f4v a1, f4v a2, f4v a3) {
        unsigned int w0, w1, w2, w3, w4, w5, w6, w7;
        asm("v_cvt_pk_bf16_f32 %0, %1, %2" : "=v"(w0) : "v"(a0[0]), "v"(a0[1]));
        asm("v_cvt_pk_bf16_f32 %0, %1, %2" : "=v"(w1) : "v"(a0[2]), "v"(a0[3]));
        asm("v_cvt_pk_bf16_f32 %0, %1, %2" : "=v"(w2) : "v"(a1[0]), "v"(a1[1]));
        asm("v_cvt_pk_bf16_f32 %0, %1, %2" : "=v"(w3) : "v"(a1[2]), "v"(a1[3]));
        asm("v_cvt_pk_bf16_f32 %0, %1, %2" : "=v"(w4) : "v"(a2[0]), "v"(a2[1]));
        asm("v_cvt_pk_bf16_f32 %0, %1, %2" : "=v"(w5) : "v"(a2[2]), "v"(a2[3]));
        asm("v_cvt_pk_bf16_f32 %0, %1, %2" : "=v"(w6) : "v"(a3[0]), "v"(a3[1]));
        asm("v_cvt_pk_bf16_f32 %0, %1, %2" : "=v"(w7) : "v"(a3[2]), "v"(a3[3]));
        u4v lo; lo[0] = w0; lo[1] = w1; lo[2] = w2; lo[3] = w3;
        u4v hi; hi[0] = w4; hi[1] = w5; hi[2] = w6; hi[3] = w7;
        char* base = (char*)&ldsA[buf][0];
        *(u4v*)(base + awb0) = lo;
        *(u4v*)(base + awb1) = hi;
    };

    int rswzA = (l15 & 7) << 4;      // read-side XOR (row&7 == l15&7)

    // prologue: tile 0 -> buf 0
    {
        f4v a0 = *(const f4v*)ap, a1 = *(const f4v*)(ap + 4);
        f4v a2 = *(const f4v*)(ap + 8), a3 = *(const f4v*)(ap + 12);
        stageB(0, 0);
        cvtwrA(0, a0, a1, a2, a3);
    }
    __syncthreads();

    for (int t = 0; t < 32; t++) {
        int buf = t & 1;
        bool pf = t < 31;
        f4v a0, a1, a2, a3;
        if (pf) {
            const float* an = ap + (t + 1) * 32;
            a0 = *(const f4v*)an; a1 = *(const f4v*)(an + 4);
            a2 = *(const f4v*)(an + 8); a3 = *(const f4v*)(an + 12);
            stageB(buf ^ 1, (t + 1) * 32);
        }
        const char* abase = (const char*)&ldsA[buf][0];
        s8v af[8], bfr[4];
#pragma unroll
        for (int m = 0; m < 8; m++) {
            int row = wr * 128 + m * 16 + l15;
            af[m] = *(const s8v*)(abase + ((row * 64 + quad * 16) ^ rswzA));
        }
#pragma unroll
        for (int n = 0; n < 4; n++)
            bfr[n] = *(const s8v*)&ldsB[buf][(wc * 64 + n * 16 + l15) * 32 + quad * 8];
#pragma unroll
        for (int m = 0; m < 8; m++)
#pragma unroll
            for (int n = 0; n < 4; n++)
                acc[m][n] = __builtin_amdgcn_mfma_f32_16x16x32_bf16(af[m], bfr[n], acc[m][n], 0, 0, 0);
        if (pf) cvtwrA(buf ^ 1, a0, a1, a2, a3);
        __syncthreads();  // drains vmcnt (B) + lgkm (A) ; reads of buf done
    }

#pragma unroll
    for (int n = 0; n < 4; n++) {
        int col = n0 + wc * 64 + n * 16 + l15;   // within 1024-wide matrix
        float bvf = bias[col];
        int hh = col >> 6, d = col & 63;
#pragma unroll
        for (int m = 0; m < 8; m++) {
#pragma unroll
            for (int r = 0; r < 4; r++) {
                int row = m0 + wr * 128 + m * 16 + quad * 4 + r;
                float v = (acc[m][n][r] + bvf) * oscale;
                int bb = row >> 11, l = row & 2047;
                if (z != 2) {
                    out[(((size_t)bb * 16 + hh) * 2048 + l) * 64 + d] = f2bf(v);
                } else {
                    int jj = l & 63;  // key -> storage slot permutation
                    int s = ((jj & 0x0C) << 2) | ((jj & 0x02) << 2) |
                            ((jj & 0x30) >> 3) | (jj & 1);
                    int lp = (l & ~63) | s;
                    out[(((size_t)bb * 16 + hh) * 64 + d) * 2048 + lp] = f2bf(v);
                }
            }
        }
    }
}

// ------- O-projection GEMM: out_fp32 = ow[8192,1024]bf16 @ WoT^T + bo ------
// m97 structure, both operands via global_load_lds, XCD-swizzled 1D grid.
__global__ __launch_bounds__(256) void ogemm(
    const unsigned short* __restrict__ A,
    const unsigned short* __restrict__ Bt,
    const float* __restrict__ bias,
    float* __restrict__ out)
{
    __shared__ __align__(16) unsigned short ldsA[2][128 * 32];
    __shared__ __align__(16) unsigned short ldsB[2][128 * 32];

    int i = blockIdx.x;                 // 512 blocks: xcd c owns 8 row-panels
    int c = i & 7, j = i >> 3;
    int bx = j & 7, by = c * 8 + (j >> 3);

    int tid = threadIdx.x;
    int w = tid >> 6, lane = tid & 63;
    int quad = lane >> 4, l15 = lane & 15;
    int wr = w >> 1, wc = w & 1;
    int m0 = by * 128, n0 = bx * 128;

    int crow = tid >> 2, ck = (tid & 3) * 8;

    f4v acc[4][4];
#pragma unroll
    for (int m = 0; m < 4; m++)
#pragma unroll
        for (int n = 0; n < 4; n++) { f4v zz = {0.f, 0.f, 0.f, 0.f}; acc[m][n] = zz; }

    auto stage = [&](int buf, int k0) {
        const unsigned short* ga = A + (size_t)(m0 + crow) * 1024 + k0 + ck;
        GLOAD_LDS(ga, &ldsA[buf][w * 512]);
        GLOAD_LDS(ga + (size_t)64 * 1024, &ldsA[buf][2048 + w * 512]);
        const unsigned short* gb = Bt + (size_t)(n0 + crow) * 1024 + k0 + ck;
        GLOAD_LDS(gb, &ldsB[buf][w * 512]);
        GLOAD_LDS(gb + (size_t)64 * 1024, &ldsB[buf][2048 + w * 512]);
    };

    stage(0, 0);
    __syncthreads();
    for (int t = 0; t < 32; t++) {
        int buf = t & 1;
        if (t < 31) stage(buf ^ 1, (t + 1) * 32);
        s8v af[4], bfr[4];
#pragma unroll
        for (int m = 0; m < 4; m++)
            af[m] = *(const s8v*)&ldsA[buf][(wr * 64 + m * 16 + l15) * 32 + quad * 8];
#pragma unroll
        for (int n = 0; n < 4; n++)
            bfr[n] = *(const s8v*)&ldsB[buf][(wc * 64 + n * 16 + l15) * 32 + quad * 8];
#pragma unroll
        for (int m = 0; m < 4; m++)
#pragma unroll
            for (int n = 0; n < 4; n++)
                acc[m][n] = __builtin_amdgcn_mfma_f32_16x16x32_bf16(af[m], bfr[n], acc[m][n], 0, 0, 0);
        __syncthreads();
    }

#pragma unroll
    for (int n = 0; n < 4; n++) {
        int col = n0 + wc * 64 + n * 16 + l15;
        float bvf = bias[col];
#pragma unroll
        for (int m = 0; m < 4; m++)
#pragma unroll
            for (int r = 0; r < 4; r++) {
                int row = m0 + wr * 64 + m * 16 + quad * 4 + r;
                out[(size_t)row * 1024 + col] = acc[m][n][r] + bvf;
            }
    }
}

// ------- Flash attention (causal), swapped-QK^T, LDS-shared K/V ------------
// (unchanged — 89 us, verified)
__global__ __launch_bounds__(256) void attn_kernel(
    const unsigned short* __restrict__ Q,
    const unsigned short* __restrict__ K,
    const unsigned short* __restrict__ Vt,
    unsigned short* __restrict__ O)
{
    __shared__ __align__(16) unsigned short Kb[2][64 * 64];
    __shared__ __align__(16) unsigned short Vb[2][64 * 64];

    int tid = threadIdx.x;
    int w = tid >> 6, lane = tid & 63;
    int quad = lane >> 4, l15 = lane & 15;

    int bid = blockIdx.x;
    int swz = (bid & 7) * 128 + (bid >> 3);
    int xp = swz & 15;
    int h = (swz >> 4) & 15;
    int b = swz >> 8;
    int bh = b * 16 + h;

    int srow = tid >> 3;
    int soff = ((tid & 7) * 16) ^ ((srow & 7) << 4);
    const unsigned short* Kbase = K + (size_t)bh * 2048 * 64;
    const unsigned short* Vbase = Vt + (size_t)bh * 64 * 2048;

    auto stageK = [&](int buf, int kt) {
        const unsigned short* g1 = Kbase + (size_t)(kt * 64 + srow) * 64 + (soff >> 1);
        GLOAD_LDS(g1, &Kb[buf][w * 512]);
        GLOAD_LDS(g1 + (size_t)32 * 64, &Kb[buf][2048 + w * 512]);
    };
    auto stageV = [&](int buf, int kt) {
        const unsigned short* g1 = Vbase + (size_t)srow * 2048 + kt * 64 + (soff >> 1);
        GLOAD_LDS(g1, &Vb[buf][w * 512]);
        GLOAD_LDS(g1 + (size_t)32 * 2048, &Vb[buf][2048 + w * 512]);
    };

    int rswz = (l15 & 7) << 4;

#pragma unroll 1
    for (int half = 0; half < 2; half++) {
        int qt = half ? 31 - xp : xp;
        int m0 = qt * 64 + w * 16;

        const unsigned short* qb = Q + ((size_t)bh * 2048 + m0 + l15) * 64 + quad * 8;
        s8v aq0 = ld8(qb), aq1 = ld8(qb + 32);

        float mrun = -1e30f, lsum = 0.f;
        f4v oacc[4];
#pragma unroll
        for (int t = 0; t < 4; t++) { f4v z = {0.f, 0.f, 0.f, 0.f}; oacc[t] = z; }

        stageK(0, 0);
        stageV(0, 0);
        __syncthreads();

#pragma unroll 1
        for (int kt = 0; kt <= qt; kt++) {
            int buf = kt & 1;
            if (kt < qt) { stageK(buf ^ 1, kt + 1); stageV(buf ^ 1, kt + 1); }

            f4v sacc[4];
#pragma unroll
            for (int t = 0; t < 4; t++) { f4v z = {0.f, 0.f, 0.f, 0.f}; sacc[t] = z; }
            const char* kbp = (const char*)&Kb[buf][0];
#pragma unroll
            for (int t = 0; t < 4; t++) {
                int rb = (t * 16 + l15) * 128;
                s8v k0 = *(const s8v*)(kbp + rb + ((quad * 16) ^ rswz));
                s8v k1 = *(const s8v*)(kbp + rb + ((64 + quad * 16) ^ rswz));
                sacc[t] = __builtin_amdgcn_mfma_f32_16x16x32_bf16(k0, aq0, sacc[t], 0, 0, 0);
                sacc[t] = __builtin_amdgcn_mfma_f32_16x16x32_bf16(k1, aq1, sacc[t], 0, 0, 0);
            }

            if (kt == qt) {
                int qrow = w * 16 + l15;
#pragma unroll
                for (int t = 0; t < 4; t++)
#pragma unroll
                    for (int r = 0; r < 4; r++) {
                        int key = t * 16 + quad * 4 + r;
                        if (key > qrow) sacc[t][r] = -1e30f;
                    }
            }

            float mx = sacc[0][0];
#pragma unroll
            for (int t = 0; t < 4; t++)
#pragma unroll
                for (int r = 0; r < 4; r++)
                    mx = fmaxf(mx, sacc[t][r]);
            mx = fmaxf(mx, __shfl_xor(mx, 16));
            mx = fmaxf(mx, __shfl_xor(mx, 32));

            if (__any(mx > mrun + 8.0f)) {
                float mnew = fmaxf(mrun, mx);
                float alpha = exp2f(mrun - mnew);
                lsum *= alpha;
#pragma unroll
                for (int r = 0; r < 4; r++) {
                    float ar = __shfl(alpha, quad * 4 + r);
#pragma unroll
                    for (int t2 = 0; t2 < 4; t2++) oacc[t2][r] *= ar;
                }
                mrun = mnew;
            }

            float rs = 0.f;
#pragma unroll
            for (int t = 0; t < 4; t++)
#pragma unroll
                for (int r = 0; r < 4; r++) {
                    float p = exp2f(sacc[t][r] - mrun);
                    rs += p;
                    sacc[t][r] = p;
                }
            lsum += rs;

            unsigned int pwv[4][2];
#pragma unroll
            for (int t = 0; t < 4; t++) {
                asm("v_cvt_pk_bf16_f32 %0, %1, %2"
                    : "=v"(pwv[t][0]) : "v"(sacc[t][0]), "v"(sacc[t][1]));
                asm("v_cvt_pk_bf16_f32 %0, %1, %2"
                    : "=v"(pwv[t][1]) : "v"(sacc[t][2]), "v"(sacc[t][3]));
            }

            const char* vbp = (const char*)&Vb[buf][0];
#pragma unroll
            for (int c = 0; c < 2; c++) {
                u4v aw;
                aw[0] = pwv[0][c]; aw[1] = pwv[1][c];
                aw[2] = pwv[2][c]; aw[3] = pwv[3][c];
                s8v apf = __builtin_bit_cast(s8v, aw);
#pragma unroll
                for (int t2 = 0; t2 < 4; t2++) {
                    int rb = (t2 * 16 + l15) * 128;
                    s8v bvv = *(const s8v*)(vbp + rb + ((quad * 32 + c * 16) ^ rswz));
                    oacc[t2] = __builtin_amdgcn_mfma_f32_16x16x32_bf16(apf, bvv, oacc[t2], 0, 0, 0);
                }
            }
            __syncthreads();
        }

        float ltot = lsum;
        ltot += __shfl_xor(ltot, 16);
        ltot += __shfl_xor(ltot, 32);
        float inv = 1.f / ltot;
#pragma unroll
        for (int r = 0; r < 4; r++) {
            float ir = __shfl(inv, quad * 4 + r);
            int l = m0 + quad * 4 + r;
#pragma unroll
            for (int t2 = 0; t2 < 4; t2++) {
                O[((size_t)b * 2048 + l) * 1024 + h * 64 + t2 * 16 + l15] = f2bf(oacc[t2][r] * ir);
            }
        }
    }
}

// ------- launch ------------------------------------------------------------
extern "C" void kernel_launch(void* const* d_in, const int* in_sizes, int n_in,
                              void* d_out, int out_size, void* d_ws, size_t ws_size,
                              hipStream_t stream)
{
    const float* queries = (const float*)d_in[0];
    const float* keys    = (const float*)d_in[1];
    const float* values  = (const float*)d_in[2];
    const float* Wq = (const float*)d_in[3];
    const float* bq = (const float*)d_in[4];
    const float* Wk = (const float*)d_in[5];
    const float* bk = (const float*)d_in[6];
    const float* Wv = (const float*)d_in[7];
    const float* bv = (const float*)d_in[8];
    const float* Wo = (const float*)d_in[9];
    const float* bo = (const float*)d_in[10];

    // ws (bf16 elems): 4x1M W^T + 3x8M Q/K/V^T + 8M ow = 72 MB
    unsigned short* ws = (unsigned short*)d_ws;
    const size_t M1 = 1u << 20, M8 = 8u << 20;
    unsigned short* WqT = ws;
    unsigned short* WkT = ws + 1 * M1;
    unsigned short* WvT = ws + 2 * M1;
    unsigned short* WoT = ws + 3 * M1;
    unsigned short* qw  = ws + 4 * M1;      // [B,H,L,64]
    unsigned short* kw  = qw + M8;          // [B,H,L,64]
    unsigned short* vtw = kw + M8;          // [B,H,64,L] (key-permuted)
    unsigned short* ow  = vtw + M8;         // [B*L,1024]

    const float sscale = 0.125f * LOG2E;

    dim3 tb(32, 8);
    transpose_w4<<<dim3(32, 32, 4), tb, 0, stream>>>(
        Wq, Wk, Wv, Wo, WqT, WkT, WvT, WoT);

    qkv_gemm<<<dim3(384), 512, 0, stream>>>(
        queries, keys, values, WqT, WkT, WvT, bq, bk, bv,
        qw, kw, vtw, sscale);

    attn_kernel<<<dim3(1024), 256, 0, stream>>>(qw, kw, vtw, ow);

    ogemm<<<dim3(512), 256, 0, stream>>>(ow, WoT, bo, (float*)d_out);
}

// Round 8
// 388.611 us; speedup vs baseline: 1.0433x; 1.0433x over previous
//
#include <hip/hip_runtime.h>

typedef __attribute__((ext_vector_type(8))) short s8v;
typedef __attribute__((ext_vector_type(4))) short s4v;
typedef __attribute__((ext_vector_type(4))) float f4v;
typedef __attribute__((ext_vector_type(4))) unsigned int u4v;

#define LOG2E 1.44269504088896340736f

__device__ __forceinline__ unsigned short f2bf(float f) {
    unsigned int x = __float_as_uint(f);
    return (unsigned short)((x + 0x7fffu + ((x >> 16) & 1u)) >> 16);
}
__device__ __forceinline__ s8v ld8(const unsigned short* p) {
    return *(const s8v*)p;
}
__device__ __forceinline__ s8v cvt8(const float* p) {
    f4v lo = *(const f4v*)p, hi = *(const f4v*)(p + 4);
    s8v r;
    r[0] = (short)f2bf(lo[0]); r[1] = (short)f2bf(lo[1]);
    r[2] = (short)f2bf(lo[2]); r[3] = (short)f2bf(lo[3]);
    r[4] = (short)f2bf(hi[0]); r[5] = (short)f2bf(hi[1]);
    r[6] = (short)f2bf(hi[2]); r[7] = (short)f2bf(hi[3]);
    return r;
}

// async global->LDS, 16B per lane; LDS dest is wave-uniform base + lane*16
#define GLOAD_LDS(g, l) __builtin_amdgcn_global_load_lds(              \
    (const __attribute__((address_space(1))) void*)(const void*)(g),   \
    (__attribute__((address_space(3))) void*)(void*)(l), 16, 0, 0)

// ------- 4x W transpose + fp32->bf16 in one launch -------------------------
__global__ __launch_bounds__(256) void transpose_w4(
    const float* __restrict__ W0, const float* __restrict__ W1,
    const float* __restrict__ W2, const float* __restrict__ W3,
    unsigned short* __restrict__ T0, unsigned short* __restrict__ T1,
    unsigned short* __restrict__ T2, unsigned short* __restrict__ T3)
{
    __shared__ float tile[32][33];
    int z = blockIdx.z;
    const float* W = z == 0 ? W0 : z == 1 ? W1 : z == 2 ? W2 : W3;
    unsigned short* Wt = z == 0 ? T0 : z == 1 ? T1 : z == 2 ? T2 : T3;
    int tx = threadIdx.x, ty = threadIdx.y;
    int x = blockIdx.x * 32 + tx;
#pragma unroll
    for (int i = 0; i < 4; i++) {
        int y = blockIdx.y * 32 + ty + i * 8;
        tile[ty + i * 8][tx] = W[y * 1024 + x];
    }
    __syncthreads();
    int x2 = blockIdx.y * 32 + tx;
#pragma unroll
    for (int i = 0; i < 4; i++) {
        int y2 = blockIdx.x * 32 + ty + i * 8;
        Wt[y2 * 1024 + x2] = f2bf(tile[tx][ty + i * 8]);
    }
}

// ------- activation fp32 -> bf16 (vectorized, grid-stride; proven r2) ------
__global__ __launch_bounds__(256) void cvt_bf16(
    const float* __restrict__ in, unsigned short* __restrict__ out, int n8)
{
    int stride = gridDim.x * 256;
    for (int i = blockIdx.x * 256 + threadIdx.x; i < n8; i += stride)
        *(s8v*)(out + (size_t)i * 8) = cvt8(in + (size_t)i * 8);
}

// ------- GEMM, counted-vmcnt triple-buffer (T3+T4), 128x128, BK=32 ---------
// A, Bt both bf16 [*,1024].  Both staged via global_load_lds with
// PRE-SWIZZLED SOURCE (chunk qp holds global chunk qp^(row&3)) + same XOR on
// the ds_read side (rule #21) -> 2-way (free) instead of 8-way conflicts.
// Schedule: stage(t+2) ; ds_read(t) ; MFMA ; s_waitcnt vmcnt(4) ; s_barrier.
// vmcnt(4) leaves this iter's 4 loads in flight, guarantees t+1 resident —
// never drains to 0 in the loop (T4).  LDS 48 KB -> 2 blocks/CU; grid 512
// = one full generation.  4 waves 2x2, 64x64 per wave.
// mode 0: FP32 [row][col].  mode 1: bf16 [b,h,l,d].  mode 2: bf16
// [b,h,d,l'] key-permuted (PV fragment layout).  oscale on (acc+bias).
__global__ __launch_bounds__(256) void gemm_ctd(
    const unsigned short* __restrict__ A,
    const unsigned short* __restrict__ Bt,
    const float* __restrict__ bias,
    void* __restrict__ outv, int mode, float oscale)
{
    __shared__ __align__(16) unsigned short ldsA[3][128 * 32];
    __shared__ __align__(16) unsigned short ldsB[3][128 * 32];

    int i = blockIdx.x;                 // 512 blocks: xcd c owns 8 M-panels
    int c = i & 7, j = i >> 3;
    int bx = j & 7, by = c * 8 + (j >> 3);

    int tid = threadIdx.x;
    int w = tid >> 6, lane = tid & 63;
    int quad = lane >> 4, l15 = lane & 15;
    int wr = w >> 1, wc = w & 1;
    int m0 = by * 128, n0 = bx * 128;

    // staging: chunk c1=tid (rows 0..63), c2=tid+256 (rows 64..127);
    // source chunk = qp ^ (row&3)  (row&3 identical for r1,r2 since 64%4==0)
    int r1 = tid >> 2, qp = tid & 3;
    int qs = (qp ^ (r1 & 3)) * 8;
    const unsigned short* ga1 = A  + (size_t)(m0 + r1) * 1024 + qs;
    const unsigned short* ga2 = A  + (size_t)(m0 + r1 + 64) * 1024 + qs;
    const unsigned short* gb1 = Bt + (size_t)(n0 + r1) * 1024 + qs;
    const unsigned short* gb2 = Bt + (size_t)(n0 + r1 + 64) * 1024 + qs;

    f4v acc[4][4];
#pragma unroll
    for (int m = 0; m < 4; m++)
#pragma unroll
        for (int n = 0; n < 4; n++) { f4v zz = {0.f, 0.f, 0.f, 0.f}; acc[m][n] = zz; }

    auto stage = [&](int buf, int k0) {
        GLOAD_LDS(ga1 + k0, &ldsA[buf][w * 512]);
        GLOAD_LDS(ga2 + k0, &ldsA[buf][2048 + w * 512]);
        GLOAD_LDS(gb1 + k0, &ldsB[buf][w * 512]);
        GLOAD_LDS(gb2 + k0, &ldsB[buf][2048 + w * 512]);
    };

    int xr = (l15 & 3) << 4;            // read-side XOR (row&3 == l15&3)

    stage(0, 0);
    stage(1, 32);
    asm volatile("s_waitcnt vmcnt(4)" ::: "memory");   // tile 0 resident
    asm volatile("s_barrier" ::: "memory");

    int buf = 0;
    for (int t = 0; t < 32; t++) {
        if (t < 30) {
            int nb = buf + 2; if (nb >= 3) nb -= 3;
            stage(nb, (t + 2) * 32);    // 4 loads in flight across barrier
        }
        const char* ab = (const char*)&ldsA[buf][0];
        const char* bb = (const char*)&ldsB[buf][0];
        s8v af[4], bfr[4];
#pragma unroll
        for (int m = 0; m < 4; m++)
            af[m] = *(const s8v*)(ab + (wr * 64 + m * 16 + l15) * 64 + ((quad * 16) ^ xr));
#pragma unroll
        for (int n = 0; n < 4; n++)
            bfr[n] = *(const s8v*)(bb + (wc * 64 + n * 16 + l15) * 64 + ((quad * 16) ^ xr));
        __builtin_amdgcn_s_setprio(1);
#pragma unroll
        for (int m = 0; m < 4; m++)
#pragma unroll
            for (int n = 0; n < 4; n++)
                acc[m][n] = __builtin_amdgcn_mfma_f32_16x16x32_bf16(af[m], bfr[n], acc[m][n], 0, 0, 0);
        __builtin_amdgcn_s_setprio(0);
        if (t < 31) {
            if (t < 30) asm volatile("s_waitcnt vmcnt(4)" ::: "memory");  // t+1 done
            else        asm volatile("s_waitcnt vmcnt(0)" ::: "memory");  // last tile
            asm volatile("s_barrier" ::: "memory");
            __builtin_amdgcn_sched_barrier(0);
        }
        buf++; if (buf >= 3) buf = 0;
    }

#pragma unroll
    for (int n = 0; n < 4; n++) {
        int col = n0 + wc * 64 + n * 16 + l15;
        float bvf = bias[col];
        int hh = col >> 6, d = col & 63;
#pragma unroll
        for (int m = 0; m < 4; m++) {
#pragma unroll
            for (int r = 0; r < 4; r++) {
                int row = m0 + wr * 64 + m * 16 + quad * 4 + r;
                float v = (acc[m][n][r] + bvf) * oscale;
                if (mode == 0) {
                    ((float*)outv)[(size_t)row * 1024 + col] = v;
                } else {
                    unsigned short* out = (unsigned short*)outv;
                    int bb2 = row >> 11, l = row & 2047;
                    if (mode == 1) {
                        out[(((size_t)bb2 * 16 + hh) * 2048 + l) * 64 + d] = f2bf(v);
                    } else {
                        int jj = l & 63;  // key -> storage slot permutation
                        int s = ((jj & 0x0C) << 2) | ((jj & 0x02) << 2) |
                                ((jj & 0x30) >> 3) | (jj & 1);
                        int lp = (l & ~63) | s;
                        out[(((size_t)bb2 * 16 + hh) * 64 + d) * 2048 + lp] = f2bf(v);
                    }
                }
            }
        }
    }
}

// ------- Flash attention (causal), swapped-QK^T, LDS-shared K/V ------------
// (unchanged — 89 us, verified)
__global__ __launch_bounds__(256) void attn_kernel(
    const unsigned short* __restrict__ Q,
    const unsigned short* __restrict__ K,
    const unsigned short* __restrict__ Vt,
    unsigned short* __restrict__ O)
{
    __shared__ __align__(16) unsigned short Kb[2][64 * 64];
    __shared__ __align__(16) unsigned short Vb[2][64 * 64];

    int tid = threadIdx.x;
    int w = tid >> 6, lane = tid & 63;
    int quad = lane >> 4, l15 = lane & 15;

    int bid = blockIdx.x;
    int swz = (bid & 7) * 128 + (bid >> 3);
    int xp = swz & 15;
    int h = (swz >> 4) & 15;
    int b = swz >> 8;
    int bh = b * 16 + h;

    int srow = tid >> 3;
    int soff = ((tid & 7) * 16) ^ ((srow & 7) << 4);
    const unsigned short* Kbase = K + (size_t)bh * 2048 * 64;
    const unsigned short* Vbase = Vt + (size_t)bh * 64 * 2048;

    auto stageK = [&](int buf, int kt) {
        const unsigned short* g1 = Kbase + (size_t)(kt * 64 + srow) * 64 + (soff >> 1);
        GLOAD_LDS(g1, &Kb[buf][w * 512]);
        GLOAD_LDS(g1 + (size_t)32 * 64, &Kb[buf][2048 + w * 512]);
    };
    auto stageV = [&](int buf, int kt) {
        const unsigned short* g1 = Vbase + (size_t)srow * 2048 + kt * 64 + (soff >> 1);
        GLOAD_LDS(g1, &Vb[buf][w * 512]);
        GLOAD_LDS(g1 + (size_t)32 * 2048, &Vb[buf][2048 + w * 512]);
    };

    int rswz = (l15 & 7) << 4;

#pragma unroll 1
    for (int half = 0; half < 2; half++) {
        int qt = half ? 31 - xp : xp;
        int m0 = qt * 64 + w * 16;

        const unsigned short* qb = Q + ((size_t)bh * 2048 + m0 + l15) * 64 + quad * 8;
        s8v aq0 = ld8(qb), aq1 = ld8(qb + 32);

        float mrun = -1e30f, lsum = 0.f;
        f4v oacc[4];
#pragma unroll
        for (int t = 0; t < 4; t++) { f4v z = {0.f, 0.f, 0.f, 0.f}; oacc[t] = z; }

        stageK(0, 0);
        stageV(0, 0);
        __syncthreads();

#pragma unroll 1
        for (int kt = 0; kt <= qt; kt++) {
            int buf = kt & 1;
            if (kt < qt) { stageK(buf ^ 1, kt + 1); stageV(buf ^ 1, kt + 1); }

            f4v sacc[4];
#pragma unroll
            for (int t = 0; t < 4; t++) { f4v z = {0.f, 0.f, 0.f, 0.f}; sacc[t] = z; }
            const char* kbp = (const char*)&Kb[buf][0];
#pragma unroll
            for (int t = 0; t < 4; t++) {
                int rb = (t * 16 + l15) * 128;
                s8v k0 = *(const s8v*)(kbp + rb + ((quad * 16) ^ rswz));
                s8v k1 = *(const s8v*)(kbp + rb + ((64 + quad * 16) ^ rswz));
                sacc[t] = __builtin_amdgcn_mfma_f32_16x16x32_bf16(k0, aq0, sacc[t], 0, 0, 0);
                sacc[t] = __builtin_amdgcn_mfma_f32_16x16x32_bf16(k1, aq1, sacc[t], 0, 0, 0);
            }

            if (kt == qt) {
                int qrow = w * 16 + l15;
#pragma unroll
                for (int t = 0; t < 4; t++)
#pragma unroll
                    for (int r = 0; r < 4; r++) {
                        int key = t * 16 + quad * 4 + r;
                        if (key > qrow) sacc[t][r] = -1e30f;
                    }
            }

            float mx = sacc[0][0];
#pragma unroll
            for (int t = 0; t < 4; t++)
#pragma unroll
                for (int r = 0; r < 4; r++)
                    mx = fmaxf(mx, sacc[t][r]);
            mx = fmaxf(mx, __shfl_xor(mx, 16));
            mx = fmaxf(mx, __shfl_xor(mx, 32));

            if (__any(mx > mrun + 8.0f)) {
                float mnew = fmaxf(mrun, mx);
                float alpha = exp2f(mrun - mnew);
                lsum *= alpha;
#pragma unroll
                for (int r = 0; r < 4; r++) {
                    float ar = __shfl(alpha, quad * 4 + r);
#pragma unroll
                    for (int t2 = 0; t2 < 4; t2++) oacc[t2][r] *= ar;
                }
                mrun = mnew;
            }

            float rs = 0.f;
#pragma unroll
            for (int t = 0; t < 4; t++)
#pragma unroll
                for (int r = 0; r < 4; r++) {
                    float p = exp2f(sacc[t][r] - mrun);
                    rs += p;
                    sacc[t][r] = p;
                }
            lsum += rs;

            unsigned int pwv[4][2];
#pragma unroll
            for (int t = 0; t < 4; t++) {
                asm("v_cvt_pk_bf16_f32 %0, %1, %2"
                    : "=v"(pwv[t][0]) : "v"(sacc[t][0]), "v"(sacc[t][1]));
                asm("v_cvt_pk_bf16_f32 %0, %1, %2"
                    : "=v"(pwv[t][1]) : "v"(sacc[t][2]), "v"(sacc[t][3]));
            }

            const char* vbp = (const char*)&Vb[buf][0];
#pragma unroll
            for (int c = 0; c < 2; c++) {
                u4v aw;
                aw[0] = pwv[0][c]; aw[1] = pwv[1][c];
                aw[2] = pwv[2][c]; aw[3] = pwv[3][c];
                s8v apf = __builtin_bit_cast(s8v, aw);
#pragma unroll
                for (int t2 = 0; t2 < 4; t2++) {
                    int rb = (t2 * 16 + l15) * 128;
                    s8v bvv = *(const s8v*)(vbp + rb + ((quad * 32 + c * 16) ^ rswz));
                    oacc[t2] = __builtin_amdgcn_mfma_f32_16x16x32_bf16(apf, bvv, oacc[t2], 0, 0, 0);
                }
            }
            __syncthreads();
        }

        float ltot = lsum;
        ltot += __shfl_xor(ltot, 16);
        ltot += __shfl_xor(ltot, 32);
        float inv = 1.f / ltot;
#pragma unroll
        for (int r = 0; r < 4; r++) {
            float ir = __shfl(inv, quad * 4 + r);
            int l = m0 + quad * 4 + r;
#pragma unroll
            for (int t2 = 0; t2 < 4; t2++) {
                O[((size_t)b * 2048 + l) * 1024 + h * 64 + t2 * 16 + l15] = f2bf(oacc[t2][r] * ir);
            }
        }
    }
}

// ------- launch ------------------------------------------------------------
extern "C" void kernel_launch(void* const* d_in, const int* in_sizes, int n_in,
                              void* d_out, int out_size, void* d_ws, size_t ws_size,
                              hipStream_t stream)
{
    const float* queries = (const float*)d_in[0];
    const float* keys    = (const float*)d_in[1];
    const float* values  = (const float*)d_in[2];
    const float* Wq = (const float*)d_in[3];
    const float* bq = (const float*)d_in[4];
    const float* Wk = (const float*)d_in[5];
    const float* bk = (const float*)d_in[6];
    const float* Wv = (const float*)d_in[7];
    const float* bv = (const float*)d_in[8];
    const float* Wo = (const float*)d_in[9];
    const float* bo = (const float*)d_in[10];

    // ws (bf16 elems): 4x1M W^T + 3x8M Q/K/V^T + 8M ow = 72 MB
    unsigned short* ws = (unsigned short*)d_ws;
    const size_t M1 = 1u << 20, M8 = 8u << 20;
    unsigned short* WqT = ws;
    unsigned short* WkT = ws + 1 * M1;
    unsigned short* WvT = ws + 2 * M1;
    unsigned short* WoT = ws + 3 * M1;
    unsigned short* qw  = ws + 4 * M1;      // [B,H,L,64]
    unsigned short* kw  = qw + M8;          // [B,H,L,64]
    unsigned short* vtw = kw + M8;          // [B,H,64,L] (key-permuted)
    unsigned short* ow  = vtw + M8;         // [B*L,1024]; cvt scratch pre-attn

    const float sscale = 0.125f * LOG2E;
    const int n8 = (int)(M8 / 8);

    dim3 tb(32, 8);
    transpose_w4<<<dim3(32, 32, 4), tb, 0, stream>>>(
        Wq, Wk, Wv, Wo, WqT, WkT, WvT, WoT);

    cvt_bf16<<<2048, 256, 0, stream>>>(queries, ow, n8);
    gemm_ctd<<<512, 256, 0, stream>>>(ow, WqT, bq, qw, 1, sscale);
    cvt_bf16<<<2048, 256, 0, stream>>>(keys, ow, n8);
    gemm_ctd<<<512, 256, 0, stream>>>(ow, WkT, bk, kw, 1, 1.0f);
    cvt_bf16<<<2048, 256, 0, stream>>>(values, ow, n8);
    gemm_ctd<<<512, 256, 0, stream>>>(ow, WvT, bv, vtw, 2, 1.0f);

    attn_kernel<<<dim3(1024), 256, 0, stream>>>(qw, kw, vtw, ow);

    gemm_ctd<<<512, 256, 0, stream>>>(ow, WoT, bo, d_out, 0, 1.0f);
}

// Round 9
// 386.996 us; speedup vs baseline: 1.0477x; 1.0042x over previous
//
#include <hip/hip_runtime.h>

typedef __attribute__((ext_vector_type(8))) short s8v;
typedef __attribute__((ext_vector_type(4))) short s4v;
typedef __attribute__((ext_vector_type(4))) float f4v;
typedef __attribute__((ext_vector_type(4))) unsigned int u4v;

#define LOG2E 1.44269504088896340736f

__device__ __forceinline__ unsigned short f2bf(float f) {
    unsigned int x = __float_as_uint(f);
    return (unsigned short)((x + 0x7fffu + ((x >> 16) & 1u)) >> 16);
}
__device__ __forceinline__ s8v ld8(const unsigned short* p) {
    return *(const s8v*)p;
}

// async global->LDS, 16B per lane; LDS dest is wave-uniform base + lane*16
#define GLOAD_LDS(g, l) __builtin_amdgcn_global_load_lds(              \
    (const __attribute__((address_space(1))) void*)(const void*)(g),   \
    (__attribute__((address_space(3))) void*)(void*)(l), 16, 0, 0)

// ------- 4x W transpose + fp32->bf16 in one launch -------------------------
__global__ __launch_bounds__(256) void transpose_w4(
    const float* __restrict__ W0, const float* __restrict__ W1,
    const float* __restrict__ W2, const float* __restrict__ W3,
    unsigned short* __restrict__ T0, unsigned short* __restrict__ T1,
    unsigned short* __restrict__ T2, unsigned short* __restrict__ T3)
{
    __shared__ float tile[32][33];
    int z = blockIdx.z;
    const float* W = z == 0 ? W0 : z == 1 ? W1 : z == 2 ? W2 : W3;
    unsigned short* Wt = z == 0 ? T0 : z == 1 ? T1 : z == 2 ? T2 : T3;
    int tx = threadIdx.x, ty = threadIdx.y;
    int x = blockIdx.x * 32 + tx;
#pragma unroll
    for (int i = 0; i < 4; i++) {
        int y = blockIdx.y * 32 + ty + i * 8;
        tile[ty + i * 8][tx] = W[y * 1024 + x];
    }
    __syncthreads();
    int x2 = blockIdx.y * 32 + tx;
#pragma unroll
    for (int i = 0; i < 4; i++) {
        int y2 = blockIdx.x * 32 + ty + i * 8;
        Wt[y2 * 1024 + x2] = f2bf(tile[tx][ty + i * 8]);
    }
}

// ------- fused QKV GEMM, counted-vmcnt triple-buffer, fp32-A in-kernel -----
// {q,k,v}[8192,1024]fp32 @ W^T + bias, one 1536-block launch (z = blk>>9).
// 128x128 tile, BK=32, 4 waves 2x2.  B staged via global_load_lds w16 with
// pre-swizzled source chunk (qp ^ (row&3)); A fp32 reg-loaded (tile t+1 at
// iter top), cvt_pk'd and ds_written XOR-swizzled AFTER the MFMA block (T14
// late-write).  vmcnt(2) leaves B(t+2) in flight across the barrier (T4 —
// never drains to 0 in the loop).  LDS 48 KB -> 3 blocks/CU, 2 generations.
// z=0: qw [b,h,l,d] * sscale. z=1: kw. z=2: vtw [b,h,d,l'] key-permuted.
__global__ __launch_bounds__(256) void qkv_fused(
    const float* __restrict__ Aq, const float* __restrict__ Ak,
    const float* __restrict__ Avv,
    const unsigned short* __restrict__ BtQ, const unsigned short* __restrict__ BtK,
    const unsigned short* __restrict__ BtV,
    const float* __restrict__ bq, const float* __restrict__ bk,
    const float* __restrict__ bv,
    unsigned short* __restrict__ qo, unsigned short* __restrict__ ko,
    unsigned short* __restrict__ vo, float sscale)
{
    __shared__ __align__(16) unsigned short ldsA[3][128 * 32];
    __shared__ __align__(16) unsigned short ldsB[3][128 * 32];

    int i = blockIdx.x;
    int z = i >> 9;                      // 0:Q 1:K 2:V (512 blocks each)
    int r = i & 511;
    int c = r & 7, j = r >> 3;           // xcd c owns 8 M-panels x 8 cols
    int bx = j & 7, by = c * 8 + (j >> 3);

    const float* A = z == 0 ? Aq : z == 1 ? Ak : Avv;
    const unsigned short* Bt = z == 0 ? BtQ : z == 1 ? BtK : BtV;
    const float* bias = z == 0 ? bq : z == 1 ? bk : bv;
    unsigned short* out = z == 0 ? qo : z == 1 ? ko : vo;
    float oscale = z == 0 ? sscale : 1.0f;

    int tid = threadIdx.x;
    int w = tid >> 6, lane = tid & 63;
    int quad = lane >> 4, l15 = lane & 15;
    int wr = w >> 1, wc = w & 1;
    int m0 = by * 128, n0 = bx * 128;

    // B staging: chunks tid (rows 0..63) and tid+256 (rows 64..127),
    // source chunk = qp ^ (row&3)
    int r1 = tid >> 2, qp = tid & 3;
    int qs = (qp ^ (r1 & 3)) * 8;
    const unsigned short* gb1 = Bt + (size_t)(n0 + r1) * 1024 + qs;
    const unsigned short* gb2 = Bt + (size_t)(n0 + r1 + 64) * 1024 + qs;

    // A reg-staging: row = tid>>1, half = tid&1 (16 fp32 each)
    int arow = tid >> 1, ahalf = tid & 1;
    const float* ap = A + (size_t)(m0 + arow) * 1024 + ahalf * 16;
    int awb0 = arow * 64 + (((2 * ahalf)     ^ (arow & 3)) << 4);
    int awb1 = arow * 64 + (((2 * ahalf + 1) ^ (arow & 3)) << 4);

    f4v acc[4][4];
#pragma unroll
    for (int m = 0; m < 4; m++)
#pragma unroll
        for (int n = 0; n < 4; n++) { f4v zz = {0.f, 0.f, 0.f, 0.f}; acc[m][n] = zz; }

    auto stageB = [&](int buf, int k0) {
        GLOAD_LDS(gb1 + k0, &ldsB[buf][w * 512]);
        GLOAD_LDS(gb2 + k0, &ldsB[buf][2048 + w * 512]);
    };
    auto cvtwrA = [&](int buf, f4v a0, f4v a1, f4v a2, f4v a3) {
        unsigned int w0, w1, w2, w3, w4, w5, w6, w7;
        asm("v_cvt_pk_bf16_f32 %0, %1, %2" : "=v"(w0) : "v"(a0[0]), "v"(a0[1]));
        asm("v_cvt_pk_bf16_f32 %0, %1, %2" : "=v"(w1) : "v"(a0[2]), "v"(a0[3]));
        asm("v_cvt_pk_bf16_f32 %0, %1, %2" : "=v"(w2) : "v"(a1[0]), "v"(a1[1]));
        asm("v_cvt_pk_bf16_f32 %0, %1, %2" : "=v"(w3) : "v"(a1[2]), "v"(a1[3]));
        asm("v_cvt_pk_bf16_f32 %0, %1, %2" : "=v"(w4) : "v"(a2[0]), "v"(a2[1]));
        asm("v_cvt_pk_bf16_f32 %0, %1, %2" : "=v"(w5) : "v"(a2[2]), "v"(a2[3]));
        asm("v_cvt_pk_bf16_f32 %0, %1, %2" : "=v"(w6) : "v"(a3[0]), "v"(a3[1]));
        asm("v_cvt_pk_bf16_f32 %0, %1, %2" : "=v"(w7) : "v"(a3[2]), "v"(a3[3]));
        u4v lo; lo[0] = w0; lo[1] = w1; lo[2] = w2; lo[3] = w3;
        u4v hi; hi[0] = w4; hi[1] = w5; hi[2] = w6; hi[3] = w7;
        char* base = (char*)&ldsA[buf][0];
        *(u4v*)(base + awb0) = lo;
        *(u4v*)(base + awb1) = hi;
    };

    int xr = (l15 & 3) << 4;             // read-side XOR (row&3 == l15&3)

    // prologue: A(0) regs + B(0),B(1) staged; A(0) written to bufA0
    {
        f4v a0 = *(const f4v*)ap,       a1 = *(const f4v*)(ap + 4);
        f4v a2 = *(const f4v*)(ap + 8), a3 = *(const f4v*)(ap + 12);
        stageB(0, 0);
        stageB(1, 32);
        asm volatile("s_waitcnt vmcnt(2)" ::: "memory");   // A0+B0 done, B1 in flight
        cvtwrA(0, a0, a1, a2, a3);
        asm volatile("s_waitcnt lgkmcnt(0)" ::: "memory");
        asm volatile("s_barrier" ::: "memory");
    }

    int buf = 0;
    for (int t = 0; t < 32; t++) {
        if (t < 30) {
            int nb = buf + 2; if (nb >= 3) nb -= 3;
            stageB(nb, (t + 2) * 32);    // B(t+2): stays in flight past barrier
        }
        f4v a0, a1, a2, a3;
        if (t < 31) {
            const float* an = ap + (t + 1) * 32;
            a0 = *(const f4v*)an;       a1 = *(const f4v*)(an + 4);
            a2 = *(const f4v*)(an + 8); a3 = *(const f4v*)(an + 12);
        }
        const char* ab = (const char*)&ldsA[buf][0];
        const char* bb = (const char*)&ldsB[buf][0];
        s8v af[4], bfr[4];
#pragma unroll
        for (int m = 0; m < 4; m++)
            af[m] = *(const s8v*)(ab + (wr * 64 + m * 16 + l15) * 64 + ((quad * 16) ^ xr));
#pragma unroll
        for (int n = 0; n < 4; n++)
            bfr[n] = *(const s8v*)(bb + (wc * 64 + n * 16 + l15) * 64 + ((quad * 16) ^ xr));
        __builtin_amdgcn_s_setprio(1);
#pragma unroll
        for (int m = 0; m < 4; m++)
#pragma unroll
            for (int n = 0; n < 4; n++)
                acc[m][n] = __builtin_amdgcn_mfma_f32_16x16x32_bf16(af[m], bfr[n], acc[m][n], 0, 0, 0);
        __builtin_amdgcn_s_setprio(0);
        if (t < 31) {
            if (t < 30) asm volatile("s_waitcnt vmcnt(2)" ::: "memory");  // A(t+1),B(t+1) done
            else        asm volatile("s_waitcnt vmcnt(0)" ::: "memory");
            int nb1 = buf + 1; if (nb1 >= 3) nb1 -= 3;
            cvtwrA(nb1, a0, a1, a2, a3);                   // A(t+1) -> buf (t+1)%3
            asm volatile("s_waitcnt lgkmcnt(0)" ::: "memory");
            asm volatile("s_barrier" ::: "memory");
            __builtin_amdgcn_sched_barrier(0);
        }
        buf++; if (buf >= 3) buf = 0;
    }

#pragma unroll
    for (int n = 0; n < 4; n++) {
        int col = n0 + wc * 64 + n * 16 + l15;
        float bvf = bias[col];
        int hh = col >> 6, d = col & 63;
#pragma unroll
        for (int m = 0; m < 4; m++) {
#pragma unroll
            for (int r2 = 0; r2 < 4; r2++) {
                int row = m0 + wr * 64 + m * 16 + quad * 4 + r2;
                float v = (acc[m][n][r2] + bvf) * oscale;
                int bb2 = row >> 11, l = row & 2047;
                if (z != 2) {
                    out[(((size_t)bb2 * 16 + hh) * 2048 + l) * 64 + d] = f2bf(v);
                } else {
                    int jj = l & 63;  // key -> storage slot permutation
                    int s = ((jj & 0x0C) << 2) | ((jj & 0x02) << 2) |
                            ((jj & 0x30) >> 3) | (jj & 1);
                    int lp = (l & ~63) | s;
                    out[(((size_t)bb2 * 16 + hh) * 64 + d) * 2048 + lp] = f2bf(v);
                }
            }
        }
    }
}

// ------- O-projection GEMM, counted-vmcnt triple-buffer (r8, verified) -----
__global__ __launch_bounds__(256) void gemm_ctd(
    const unsigned short* __restrict__ A,
    const unsigned short* __restrict__ Bt,
    const float* __restrict__ bias,
    float* __restrict__ out)
{
    __shared__ __align__(16) unsigned short ldsA[3][128 * 32];
    __shared__ __align__(16) unsigned short ldsB[3][128 * 32];

    int i = blockIdx.x;
    int c = i & 7, j = i >> 3;
    int bx = j & 7, by = c * 8 + (j >> 3);

    int tid = threadIdx.x;
    int w = tid >> 6, lane = tid & 63;
    int quad = lane >> 4, l15 = lane & 15;
    int wr = w >> 1, wc = w & 1;
    int m0 = by * 128, n0 = bx * 128;

    int r1 = tid >> 2, qp = tid & 3;
    int qs = (qp ^ (r1 & 3)) * 8;
    const unsigned short* ga1 = A  + (size_t)(m0 + r1) * 1024 + qs;
    const unsigned short* ga2 = A  + (size_t)(m0 + r1 + 64) * 1024 + qs;
    const unsigned short* gb1 = Bt + (size_t)(n0 + r1) * 1024 + qs;
    const unsigned short* gb2 = Bt + (size_t)(n0 + r1 + 64) * 1024 + qs;

    f4v acc[4][4];
#pragma unroll
    for (int m = 0; m < 4; m++)
#pragma unroll
        for (int n = 0; n < 4; n++) { f4v zz = {0.f, 0.f, 0.f, 0.f}; acc[m][n] = zz; }

    auto stage = [&](int buf, int k0) {
        GLOAD_LDS(ga1 + k0, &ldsA[buf][w * 512]);
        GLOAD_LDS(ga2 + k0, &ldsA[buf][2048 + w * 512]);
        GLOAD_LDS(gb1 + k0, &ldsB[buf][w * 512]);
        GLOAD_LDS(gb2 + k0, &ldsB[buf][2048 + w * 512]);
    };

    int xr = (l15 & 3) << 4;

    stage(0, 0);
    stage(1, 32);
    asm volatile("s_waitcnt vmcnt(4)" ::: "memory");
    asm volatile("s_barrier" ::: "memory");

    int buf = 0;
    for (int t = 0; t < 32; t++) {
        if (t < 30) {
            int nb = buf + 2; if (nb >= 3) nb -= 3;
            stage(nb, (t + 2) * 32);
        }
        const char* ab = (const char*)&ldsA[buf][0];
        const char* bb = (const char*)&ldsB[buf][0];
        s8v af[4], bfr[4];
#pragma unroll
        for (int m = 0; m < 4; m++)
            af[m] = *(const s8v*)(ab + (wr * 64 + m * 16 + l15) * 64 + ((quad * 16) ^ xr));
#pragma unroll
        for (int n = 0; n < 4; n++)
            bfr[n] = *(const s8v*)(bb + (wc * 64 + n * 16 + l15) * 64 + ((quad * 16) ^ xr));
        __builtin_amdgcn_s_setprio(1);
#pragma unroll
        for (int m = 0; m < 4; m++)
#pragma unroll
            for (int n = 0; n < 4; n++)
                acc[m][n] = __builtin_amdgcn_mfma_f32_16x16x32_bf16(af[m], bfr[n], acc[m][n], 0, 0, 0);
        __builtin_amdgcn_s_setprio(0);
        if (t < 31) {
            if (t < 30) asm volatile("s_waitcnt vmcnt(4)" ::: "memory");
            else        asm volatile("s_waitcnt vmcnt(0)" ::: "memory");
            asm volatile("s_barrier" ::: "memory");
            __builtin_amdgcn_sched_barrier(0);
        }
        buf++; if (buf >= 3) buf = 0;
    }

#pragma unroll
    for (int n = 0; n < 4; n++) {
        int col = n0 + wc * 64 + n * 16 + l15;
        float bvf = bias[col];
#pragma unroll
        for (int m = 0; m < 4; m++)
#pragma unroll
            for (int r2 = 0; r2 < 4; r2++) {
                int row = m0 + wr * 64 + m * 16 + quad * 4 + r2;
                out[(size_t)row * 1024 + col] = acc[m][n][r2] + bvf;
            }
    }
}

// ------- Flash attention (causal), swapped-QK^T, LDS-shared K/V ------------
// r8 structure + tree-shaped max/sum reductions (serial 16-dep chains were
// ~256 cy/iter of pure latency; trees are depth 4).
__global__ __launch_bounds__(256) void attn_kernel(
    const unsigned short* __restrict__ Q,
    const unsigned short* __restrict__ K,
    const unsigned short* __restrict__ Vt,
    unsigned short* __restrict__ O)
{
    __shared__ __align__(16) unsigned short Kb[2][64 * 64];
    __shared__ __align__(16) unsigned short Vb[2][64 * 64];

    int tid = threadIdx.x;
    int w = tid >> 6, lane = tid & 63;
    int quad = lane >> 4, l15 = lane & 15;

    int bid = blockIdx.x;
    int swz = (bid & 7) * 128 + (bid >> 3);
    int xp = swz & 15;
    int h = (swz >> 4) & 15;
    int b = swz >> 8;
    int bh = b * 16 + h;

    int srow = tid >> 3;
    int soff = ((tid & 7) * 16) ^ ((srow & 7) << 4);
    const unsigned short* Kbase = K + (size_t)bh * 2048 * 64;
    const unsigned short* Vbase = Vt + (size_t)bh * 64 * 2048;

    auto stageK = [&](int buf, int kt) {
        const unsigned short* g1 = Kbase + (size_t)(kt * 64 + srow) * 64 + (soff >> 1);
        GLOAD_LDS(g1, &Kb[buf][w * 512]);
        GLOAD_LDS(g1 + (size_t)32 * 64, &Kb[buf][2048 + w * 512]);
    };
    auto stageV = [&](int buf, int kt) {
        const unsigned short* g1 = Vbase + (size_t)srow * 2048 + kt * 64 + (soff >> 1);
        GLOAD_LDS(g1, &Vb[buf][w * 512]);
        GLOAD_LDS(g1 + (size_t)32 * 2048, &Vb[buf][2048 + w * 512]);
    };

    int rswz = (l15 & 7) << 4;

#pragma unroll 1
    for (int half = 0; half < 2; half++) {
        int qt = half ? 31 - xp : xp;
        int m0 = qt * 64 + w * 16;

        const unsigned short* qb = Q + ((size_t)bh * 2048 + m0 + l15) * 64 + quad * 8;
        s8v aq0 = ld8(qb), aq1 = ld8(qb + 32);

        float mrun = -1e30f, lsum = 0.f;
        f4v oacc[4];
#pragma unroll
        for (int t = 0; t < 4; t++) { f4v z = {0.f, 0.f, 0.f, 0.f}; oacc[t] = z; }

        stageK(0, 0);
        stageV(0, 0);
        __syncthreads();

#pragma unroll 1
        for (int kt = 0; kt <= qt; kt++) {
            int buf = kt & 1;
            if (kt < qt) { stageK(buf ^ 1, kt + 1); stageV(buf ^ 1, kt + 1); }

            f4v sacc[4];
#pragma unroll
            for (int t = 0; t < 4; t++) { f4v z = {0.f, 0.f, 0.f, 0.f}; sacc[t] = z; }
            const char* kbp = (const char*)&Kb[buf][0];
#pragma unroll
            for (int t = 0; t < 4; t++) {
                int rb = (t * 16 + l15) * 128;
                s8v k0 = *(const s8v*)(kbp + rb + ((quad * 16) ^ rswz));
                s8v k1 = *(const s8v*)(kbp + rb + ((64 + quad * 16) ^ rswz));
                sacc[t] = __builtin_amdgcn_mfma_f32_16x16x32_bf16(k0, aq0, sacc[t], 0, 0, 0);
                sacc[t] = __builtin_amdgcn_mfma_f32_16x16x32_bf16(k1, aq1, sacc[t], 0, 0, 0);
            }

            if (kt == qt) {
                int qrow = w * 16 + l15;
#pragma unroll
                for (int t = 0; t < 4; t++)
#pragma unroll
                    for (int r = 0; r < 4; r++) {
                        int key = t * 16 + quad * 4 + r;
                        if (key > qrow) sacc[t][r] = -1e30f;
                    }
            }

            // tree max (depth 4, exact)
            float tmax[4];
#pragma unroll
            for (int t = 0; t < 4; t++)
                tmax[t] = fmaxf(fmaxf(sacc[t][0], sacc[t][1]),
                                fmaxf(sacc[t][2], sacc[t][3]));
            float mx = fmaxf(fmaxf(tmax[0], tmax[1]), fmaxf(tmax[2], tmax[3]));
            mx = fmaxf(mx, __shfl_xor(mx, 16));
            mx = fmaxf(mx, __shfl_xor(mx, 32));

            if (__any(mx > mrun + 8.0f)) {
                float mnew = fmaxf(mrun, mx);
                float alpha = exp2f(mrun - mnew);
                lsum *= alpha;
#pragma unroll
                for (int r = 0; r < 4; r++) {
                    float ar = __shfl(alpha, quad * 4 + r);
#pragma unroll
                    for (int t2 = 0; t2 < 4; t2++) oacc[t2][r] *= ar;
                }
                mrun = mnew;
            }

            // tree sum (depth 4)
            float ps[4];
#pragma unroll
            for (int t = 0; t < 4; t++) {
                float p0 = exp2f(sacc[t][0] - mrun);
                float p1 = exp2f(sacc[t][1] - mrun);
                float p2 = exp2f(sacc[t][2] - mrun);
                float p3 = exp2f(sacc[t][3] - mrun);
                sacc[t][0] = p0; sacc[t][1] = p1;
                sacc[t][2] = p2; sacc[t][3] = p3;
                ps[t] = (p0 + p1) + (p2 + p3);
            }
            lsum += (ps[0] + ps[1]) + (ps[2] + ps[3]);

            unsigned int pwv[4][2];
#pragma unroll
            for (int t = 0; t < 4; t++) {
                asm("v_cvt_pk_bf16_f32 %0, %1, %2"
                    : "=v"(pwv[t][0]) : "v"(sacc[t][0]), "v"(sacc[t][1]));
                asm("v_cvt_pk_bf16_f32 %0, %1, %2"
                    : "=v"(pwv[t][1]) : "v"(sacc[t][2]), "v"(sacc[t][3]));
            }

            const char* vbp = (const char*)&Vb[buf][0];
#pragma unroll
            for (int cc = 0; cc < 2; cc++) {
                u4v aw;
                aw[0] = pwv[0][cc]; aw[1] = pwv[1][cc];
                aw[2] = pwv[2][cc]; aw[3] = pwv[3][cc];
                s8v apf = __builtin_bit_cast(s8v, aw);
#pragma unroll
                for (int t2 = 0; t2 < 4; t2++) {
                    int rb = (t2 * 16 + l15) * 128;
                    s8v bvv = *(const s8v*)(vbp + rb + ((quad * 32 + cc * 16) ^ rswz));
                    oacc[t2] = __builtin_amdgcn_mfma_f32_16x16x32_bf16(apf, bvv, oacc[t2], 0, 0, 0);
                }
            }
            __syncthreads();
        }

        float ltot = lsum;
        ltot += __shfl_xor(ltot, 16);
        ltot += __shfl_xor(ltot, 32);
        float inv = 1.f / ltot;
#pragma unroll
        for (int r = 0; r < 4; r++) {
            float ir = __shfl(inv, quad * 4 + r);
            int l = m0 + quad * 4 + r;
#pragma unroll
            for (int t2 = 0; t2 < 4; t2++) {
                O[((size_t)b * 2048 + l) * 1024 + h * 64 + t2 * 16 + l15] = f2bf(oacc[t2][r] * ir);
            }
        }
    }
}

// ------- launch ------------------------------------------------------------
extern "C" void kernel_launch(void* const* d_in, const int* in_sizes, int n_in,
                              void* d_out, int out_size, void* d_ws, size_t ws_size,
                              hipStream_t stream)
{
    const float* queries = (const float*)d_in[0];
    const float* keys    = (const float*)d_in[1];
    const float* values  = (const float*)d_in[2];
    const float* Wq = (const float*)d_in[3];
    const float* bq = (const float*)d_in[4];
    const float* Wk = (const float*)d_in[5];
    const float* bk = (const float*)d_in[6];
    const float* Wv = (const float*)d_in[7];
    const float* bv = (const float*)d_in[8];
    const float* Wo = (const float*)d_in[9];
    const float* bo = (const float*)d_in[10];

    // ws (bf16 elems): 4x1M W^T + 3x8M Q/K/V^T + 8M ow = 72 MB
    unsigned short* ws = (unsigned short*)d_ws;
    const size_t M1 = 1u << 20, M8 = 8u << 20;
    unsigned short* WqT = ws;
    unsigned short* WkT = ws + 1 * M1;
    unsigned short* WvT = ws + 2 * M1;
    unsigned short* WoT = ws + 3 * M1;
    unsigned short* qw  = ws + 4 * M1;      // [B,H,L,64]
    unsigned short* kw  = qw + M8;          // [B,H,L,64]
    unsigned short* vtw = kw + M8;          // [B,H,64,L] (key-permuted)
    unsigned short* ow  = vtw + M8;         // [B*L,1024]

    const float sscale = 0.125f * LOG2E;

    dim3 tb(32, 8);
    transpose_w4<<<dim3(32, 32, 4), tb, 0, stream>>>(
        Wq, Wk, Wv, Wo, WqT, WkT, WvT, WoT);

    qkv_fused<<<dim3(1536), 256, 0, stream>>>(
        queries, keys, values, WqT, WkT, WvT, bq, bk, bv,
        qw, kw, vtw, sscale);

    attn_kernel<<<dim3(1024), 256, 0, stream>>>(qw, kw, vtw, ow);

    gemm_ctd<<<dim3(512), 256, 0, stream>>>(ow, WoT, bo, (float*)d_out);
}